// Round 1
// baseline (337.711 us; speedup 1.0000x reference)
//
#include <hip/hip_runtime.h>
#include <math.h>

// DiceLoss fused kernel for MI355X.
// B=32, C=1, H=W=1024 fp32. loss = mean_b(1 - (2*I_b + 1e-3)/(M_b + 1e-3))
//   I_b = sum sigmoid(o)*t*w,  M_b = sum (t+sigmoid(o))*w,
//   w = 1 + 5*|boxavg31(t) - t|, zero-padded, always /961.
//
// Structure: vertical 31-box sliding sum in registers (thread-per-column),
// horizontal 31-box via LDS staging + per-thread 8-wide register sliding
// window (10x ds_read_b128 per 8 outputs; padded LDS layout i + (i/8)*4
// keeps bank load uniform). Fused weight+sigmoid+reductions; only 64 floats
// of workspace used (per-batch accumulators).

namespace {
constexpr int Bn = 32;
constexpr int Hn = 1024;
constexpr int Wn = 1024;
constexpr int Rn = 15;           // kernel radius (K=31)
constexpr int TX = 256;          // tile width in outputs
constexpr int YS = 128;          // tile height in outputs
constexpr int NCOL = TX + 32;    // staged columns (30-halo rounded to 32)
constexpr int PHYSW = (NCOL / 8) * 12;   // 432 floats per padded LDS row
constexpr float INV_KK = 1.0f / 961.0f;
}

__device__ __forceinline__ int phys(int i) { return i + ((i >> 3) << 2); }

__device__ __forceinline__ float ldg0(const float* p, int y, int x) {
    return (y >= 0 && y < Hn && x >= 0 && x < Wn) ? p[(size_t)y * Wn + x] : 0.0f;
}

__global__ __launch_bounds__(256, 2)
void dice_main(const float* __restrict__ logits, const float* __restrict__ tgt,
               float* __restrict__ acc)
{
    __shared__ __align__(16) float vbuf[8 * PHYSW];
    __shared__ float red[8];

    const int bid = blockIdx.x;
    const int b   = bid >> 5;          // 32 tiles per batch image
    const int rem = bid & 31;
    const int x0  = (rem >> 3) * TX;   // 4 x-tiles
    const int y0  = (rem & 7) * YS;    // 8 y-tiles
    const int t   = threadIdx.x;

    const float* tb = tgt    + (size_t)b * Hn * Wn;
    const float* ob = logits + (size_t)b * Hn * Wn;

    // Each thread owns staged column index t; threads 0..31 also own 256+t.
    const int  col0 = x0 - Rn + t;
    const bool has2 = (t < 32);
    const int  col1 = col0 + 256;

    // Vertical sliding box sum init for output row y0: rows [y0-15, y0+15].
    float vs0 = 0.0f, vs1 = 0.0f;
    for (int yy = y0 - Rn; yy <= y0 + Rn; ++yy) {
        vs0 += ldg0(tb, yy, col0);
        if (has2) vs1 += ldg0(tb, yy, col1);
    }

    float acc_i = 0.0f, acc_m = 0.0f;

    for (int it = 0; it < YS / 8; ++it) {
        const int ya = y0 + it * 8;

        // Phase A: advance vertical sums, stage 8 vsum rows into LDS.
        #pragma unroll
        for (int r = 0; r < 8; ++r) {
            const int yr = ya + r;
            if (yr != y0) {
                vs0 += ldg0(tb, yr + Rn, col0) - ldg0(tb, yr - Rn - 1, col0);
                if (has2) vs1 += ldg0(tb, yr + Rn, col1) - ldg0(tb, yr - Rn - 1, col1);
            }
            vbuf[r * PHYSW + phys(t)] = vs0;
            if (has2) vbuf[r * PHYSW + phys(256 + t)] = vs1;
        }
        __syncthreads();

        // Phase B: horizontal 31-tap via register sliding window, 8 x per thread.
        {
            const int r = t >> 5;       // row within the 8-row batch
            const int j = t & 31;       // 8-wide x strip
            const int yrow = ya + r;
            const float* vrow = &vbuf[r * PHYSW];

            float w[40];
            #pragma unroll
            for (int k = 0; k < 10; ++k) {
                const int l = (j << 3) + (k << 2);      // logical offset, 16B-aligned in phys
                const float4 q = *(const float4*)&vrow[phys(l)];
                w[4 * k + 0] = q.x; w[4 * k + 1] = q.y;
                w[4 * k + 2] = q.z; w[4 * k + 3] = q.w;
            }

            const int xb = x0 + (j << 3);
            const float4* tq = (const float4*)(tb + (size_t)yrow * Wn + xb);
            const float4 t0 = tq[0], t1 = tq[1];
            const float4* oq = (const float4*)(ob + (size_t)yrow * Wn + xb);
            const float4 o0 = oq[0], o1 = oq[1];
            const float tc[8] = {t0.x, t0.y, t0.z, t0.w, t1.x, t1.y, t1.z, t1.w};
            const float oc[8] = {o0.x, o0.y, o0.z, o0.w, o1.x, o1.y, o1.z, o1.w};

            float s = 0.0f;
            #pragma unroll
            for (int c = 0; c < 31; ++c) s += w[c];
            #pragma unroll
            for (int m = 0; m < 8; ++m) {
                if (m > 0) s += w[30 + m] - w[m - 1];
                const float avg = s * INV_KK;
                const float wt  = 1.0f + 5.0f * fabsf(avg - tc[m]);
                const float sg  = 1.0f / (1.0f + __expf(-oc[m]));
                acc_i += sg * tc[m] * wt;
                acc_m += (tc[m] + sg) * wt;
            }
        }
        __syncthreads();
    }

    // Block reduction: wave shuffle, then 4 wave partials through LDS.
    #pragma unroll
    for (int off = 32; off > 0; off >>= 1) {
        acc_i += __shfl_down(acc_i, off);
        acc_m += __shfl_down(acc_m, off);
    }
    const int lane = t & 63;
    const int wv   = t >> 6;
    if (lane == 0) { red[wv * 2] = acc_i; red[wv * 2 + 1] = acc_m; }
    __syncthreads();
    if (t == 0) {
        atomicAdd(&acc[2 * b],     red[0] + red[2] + red[4] + red[6]);
        atomicAdd(&acc[2 * b + 1], red[1] + red[3] + red[5] + red[7]);
    }
}

__global__ void dice_final(const float* __restrict__ acc, float* __restrict__ out)
{
    const int t = threadIdx.x;
    float l = 0.0f;
    if (t < Bn) {
        const float I = acc[2 * t];
        const float M = acc[2 * t + 1];
        l = 1.0f - (2.0f * I + 0.001f) / (M + 0.001f);
    }
    #pragma unroll
    for (int off = 32; off > 0; off >>= 1) l += __shfl_down(l, off);
    if (t == 0) out[0] = l * (1.0f / 32.0f);
}

extern "C" void kernel_launch(void* const* d_in, const int* in_sizes, int n_in,
                              void* d_out, int out_size, void* d_ws, size_t ws_size,
                              hipStream_t stream)
{
    const float* logits = (const float*)d_in[0];   // "output" in reference
    const float* target = (const float*)d_in[1];
    float* acc = (float*)d_ws;                     // 64 floats: (I_b, M_b) per batch

    hipMemsetAsync(d_ws, 0, 64 * sizeof(float), stream);
    dice_main<<<dim3(Bn * 32), dim3(256), 0, stream>>>(logits, target, acc);
    dice_final<<<dim3(1), dim3(64), 0, stream>>>(acc, (float*)d_out);
}

// Round 2
// 317.963 us; speedup vs baseline: 1.0621x; 1.0621x over previous
//
#include <hip/hip_runtime.h>
#include <math.h>

// DiceLoss fused kernel for MI355X — round 2: software-pipelined prefetch.
// B=32, C=1, H=W=1024 fp32. loss = mean_b(1 - (2*I_b + 1e-3)/(M_b + 1e-3))
//   I_b = sum sigmoid(o)*t*w,  M_b = sum (t+sigmoid(o))*w,
//   w = 1 + 5*|boxavg31(t) - t|, zero-padded, always /961.
//
// R1 post-mortem: FETCH=268MB (minimal), BW 1.7TB/s, VALU 23% -> latency-bound.
// Loads were issued and consumed inside the same barrier-delimited phase.
// R2: prefetch one 8-row batch ahead. Vertical add-rows (HBM) and phase-B
// t/o float4 strips are loaded at the START of phase B of batch i and
// consumed in batch i+1; the compiler's vmcnt(0) drain at the phase-B-ending
// barrier completes them behind phase-B compute. Subtract rows stay direct
// loads (L2 hits per FETCH evidence). Register budget kept ~<110 so
// __launch_bounds__(256,4) holds 4 blocks/CU.

namespace {
constexpr int Bn = 32;
constexpr int Hn = 1024;
constexpr int Wn = 1024;
constexpr int Rn = 15;           // kernel radius (K=31)
constexpr int TX = 256;          // tile width in outputs
constexpr int YS = 128;          // tile height in outputs
constexpr int NB = YS / 8;       // 8-row batches per tile
constexpr int NCOL = TX + 32;    // staged columns (30-halo rounded to 32)
constexpr int PHYSW = (NCOL / 8) * 12;   // 432 floats per padded LDS row
constexpr float INV_KK = 1.0f / 961.0f;
}

__device__ __forceinline__ int phys(int i) { return i + ((i >> 3) << 2); }

// x-guard precomputed per thread; y folded to one unsigned compare.
__device__ __forceinline__ float ldcol(const float* p, int y, int col, bool xok) {
    return (xok && (unsigned)y < (unsigned)Hn) ? p[(size_t)y * Wn + col] : 0.0f;
}

__global__ __launch_bounds__(256, 4)
void dice_main(const float* __restrict__ logits, const float* __restrict__ tgt,
               float* __restrict__ acc)
{
    __shared__ __align__(16) float vbuf[8 * PHYSW];
    __shared__ float red[8];

    const int bid = blockIdx.x;
    const int b   = bid >> 5;          // 32 tiles per batch image
    const int rem = bid & 31;
    const int x0  = (rem >> 3) * TX;   // 4 x-tiles
    const int y0  = (rem & 7) * YS;    // 8 y-tiles
    const int t   = threadIdx.x;

    const float* tb = tgt    + (size_t)b * Hn * Wn;
    const float* ob = logits + (size_t)b * Hn * Wn;

    // Vertical-sum column ownership: thread t owns staged col t; t<32 also 256+t.
    const int  col0 = x0 - Rn + t;
    const bool has2 = (t < 32);
    const int  col1 = col0 + 256;
    const bool xok0 = (col0 >= 0) && (col0 < Wn);
    const bool xok1 = (col1 >= 0) && (col1 < Wn);
    const int  pt   = phys(t);
    const int  pt2  = phys(256 + t);

    // Phase-B strip identity (fixed per thread across all batches).
    const int rr = t >> 5;             // row within 8-row batch
    const int jj = t & 31;             // 8-wide x strip
    const int xb = x0 + (jj << 3);

    // ---- init: vertical box sum for output row y0 (rows y0-15..y0+15) ----
    float vs0 = 0.0f, vs1 = 0.0f;
    for (int yy = y0 - Rn; yy <= y0 + Rn; ++yy) {
        vs0 += ldcol(tb, yy, col0, xok0);
        if (has2) vs1 += ldcol(tb, yy, col1, xok1);
    }

    // ---- prefetch batch 0: vertical add-rows + phase-B t/o strips ----
    float pA[8], qA[8];
    #pragma unroll
    for (int r = 0; r < 8; ++r) {
        pA[r] = ldcol(tb, y0 + r + Rn, col0, xok0);
        qA[r] = has2 ? ldcol(tb, y0 + r + Rn, col1, xok1) : 0.0f;
    }
    float4 ct0, ct1, co0, co1;
    {
        const float* tp = tb + (size_t)(y0 + rr) * Wn + xb;
        const float* op = ob + (size_t)(y0 + rr) * Wn + xb;
        ct0 = ((const float4*)tp)[0]; ct1 = ((const float4*)tp)[1];
        co0 = ((const float4*)op)[0]; co1 = ((const float4*)op)[1];
    }

    float acc_i = 0.0f, acc_m = 0.0f;

    for (int it = 0; it < NB; ++it) {
        const int ya = y0 + it * 8;

        // ---- phase A: consume prefetched add rows, direct L2 sub loads ----
        #pragma unroll
        for (int r = 0; r < 8; ++r) {
            const int yr = ya + r;
            if (it > 0 || r > 0) {
                vs0 += pA[r] - ldcol(tb, yr - Rn - 1, col0, xok0);
                if (has2) vs1 += qA[r] - ldcol(tb, yr - Rn - 1, col1, xok1);
            }
            vbuf[r * PHYSW + pt] = vs0;
            if (has2) vbuf[r * PHYSW + pt2] = vs1;
        }
        __syncthreads();

        // ---- phase B ----
        // Issue next-batch prefetches FIRST; the barrier at the end of this
        // phase drains them behind the compute below.
        float4 nt0, nt1, no0, no1;
        if (it + 1 < NB) {
            #pragma unroll
            for (int r = 0; r < 8; ++r) {
                pA[r] = ldcol(tb, ya + 8 + r + Rn, col0, xok0);
                if (has2) qA[r] = ldcol(tb, ya + 8 + r + Rn, col1, xok1);
            }
            const float* tp = tb + (size_t)(ya + 8 + rr) * Wn + xb;
            const float* op = ob + (size_t)(ya + 8 + rr) * Wn + xb;
            nt0 = ((const float4*)tp)[0]; nt1 = ((const float4*)tp)[1];
            no0 = ((const float4*)op)[0]; no1 = ((const float4*)op)[1];
        }

        // Horizontal 31-tap: 10 aligned b128 LDS reads + register slide.
        {
            const float* vrow = &vbuf[rr * PHYSW];
            float w[40];
            #pragma unroll
            for (int k = 0; k < 10; ++k) {
                const float4 q = *(const float4*)&vrow[phys((jj << 3) + (k << 2))];
                w[4 * k + 0] = q.x; w[4 * k + 1] = q.y;
                w[4 * k + 2] = q.z; w[4 * k + 3] = q.w;
            }

            const float tc[8] = {ct0.x, ct0.y, ct0.z, ct0.w, ct1.x, ct1.y, ct1.z, ct1.w};
            const float oc[8] = {co0.x, co0.y, co0.z, co0.w, co1.x, co1.y, co1.z, co1.w};

            // balanced-ish initial 31-sum
            float s0 = 0.0f, s1 = 0.0f, s2 = 0.0f, s3 = 0.0f;
            #pragma unroll
            for (int c = 0; c < 28; c += 4) {
                s0 += w[c]; s1 += w[c + 1]; s2 += w[c + 2]; s3 += w[c + 3];
            }
            float s = (s0 + s1) + (s2 + s3) + w[28] + w[29] + w[30];
            #pragma unroll
            for (int m = 0; m < 8; ++m) {
                if (m > 0) s += w[30 + m] - w[m - 1];
                const float avg = s * INV_KK;
                const float wt  = 1.0f + 5.0f * fabsf(avg - tc[m]);
                const float sg  = 1.0f / (1.0f + __expf(-oc[m]));
                acc_i += sg * tc[m] * wt;
                acc_m += (tc[m] + sg) * wt;
            }
        }

        // rotate t/o double buffer
        if (it + 1 < NB) { ct0 = nt0; ct1 = nt1; co0 = no0; co1 = no1; }
        __syncthreads();
    }

    // ---- block reduction ----
    #pragma unroll
    for (int off = 32; off > 0; off >>= 1) {
        acc_i += __shfl_down(acc_i, off);
        acc_m += __shfl_down(acc_m, off);
    }
    const int lane = t & 63;
    const int wv   = t >> 6;
    if (lane == 0) { red[wv * 2] = acc_i; red[wv * 2 + 1] = acc_m; }
    __syncthreads();
    if (t == 0) {
        atomicAdd(&acc[2 * b],     red[0] + red[2] + red[4] + red[6]);
        atomicAdd(&acc[2 * b + 1], red[1] + red[3] + red[5] + red[7]);
    }
}

__global__ void dice_final(const float* __restrict__ acc, float* __restrict__ out)
{
    const int t = threadIdx.x;
    float l = 0.0f;
    if (t < Bn) {
        const float I = acc[2 * t];
        const float M = acc[2 * t + 1];
        l = 1.0f - (2.0f * I + 0.001f) / (M + 0.001f);
    }
    #pragma unroll
    for (int off = 32; off > 0; off >>= 1) l += __shfl_down(l, off);
    if (t == 0) out[0] = l * (1.0f / 32.0f);
}

extern "C" void kernel_launch(void* const* d_in, const int* in_sizes, int n_in,
                              void* d_out, int out_size, void* d_ws, size_t ws_size,
                              hipStream_t stream)
{
    const float* logits = (const float*)d_in[0];   // "output" in reference
    const float* target = (const float*)d_in[1];
    float* acc = (float*)d_ws;                     // 64 floats: (I_b, M_b) per batch

    hipMemsetAsync(d_ws, 0, 64 * sizeof(float), stream);
    dice_main<<<dim3(Bn * 32), dim3(256), 0, stream>>>(logits, target, acc);
    dice_final<<<dim3(1), dim3(64), 0, stream>>>(acc, (float*)d_out);
}